// Round 5
// baseline (1677.526 us; speedup 1.0000x reference)
//
#include <hip/hip_runtime.h>

#define BB    32
#define CDIM  256
#define TT    2048
#define NE    1024
#define NROWS (BB * TT)          // 65536
#define NELEM (BB * CDIM * TT)   // 16777216

// dist_argmin tiling
#define RT 128                   // rows per block
#define CT 128                   // codes per chunk
#define KC 32                    // k's per LDS stage
#define NHALF 512                // codes per block (code-split factor 2)
#define ESTRIDE 132              // es row stride (16B-aligned rows)
#define GAP_THRESH 4e-4f         // flag threshold; decision margin bound ~1.6e-4

typedef float v2f __attribute__((ext_vector_type(2)));

// ---------------------------------------------------------------------------
// numpy pairwise sum of squares over 128 elements (stride in elements):
// 8 partial accumulators, combined ((r0+r1)+(r2+r3)) + ((r4+r5)+(r6+r7)).
// fp contract OFF (numpy squares then adds, no FMA).
// ---------------------------------------------------------------------------
__device__ __forceinline__ float np_sq_sum128(const float* p, int stride) {
#pragma clang fp contract(off)
  float r[8];
#pragma unroll
  for (int j = 0; j < 8; j++) {
    float v = p[(size_t)j * stride];
    r[j] = v * v;
  }
  for (int i = 8; i < 128; i += 8) {
#pragma unroll
    for (int j = 0; j < 8; j++) {
      float v = p[(size_t)(i + j) * stride];
      float s = v * v;
      r[j] += s;
    }
  }
  return ((r[0] + r[1]) + (r[2] + r[3])) + ((r[4] + r[5]) + (r[6] + r[7]));
}

__global__ __launch_bounds__(256) void e2_kernel(const float* __restrict__ cb,
                                                 float* __restrict__ e2) {
#pragma clang fp contract(off)
  int k = blockIdx.x * 256 + threadIdx.x;
  if (k >= NE) return;
  const float* p = cb + (size_t)k * CDIM;
  float h0 = np_sq_sum128(p, 1);
  float h1 = np_sq_sum128(p + 128, 1);
  e2[k] = h0 + h1;
}

__global__ __launch_bounds__(256) void z2_kernel(const float* __restrict__ z,
                                                 float* __restrict__ z2) {
#pragma clang fp contract(off)
  int n = blockIdx.x * 256 + threadIdx.x;
  if (n >= NROWS) return;
  int b = n >> 11;
  int t = n & (TT - 1);
  const float* p = z + (size_t)b * CDIM * TT + t;
  float h0 = np_sq_sum128(p, TT);
  float h1 = np_sq_sum128(p + (size_t)128 * TT, TT);
  z2[n] = h0 + h1;
}

// ---------------------------------------------------------------------------
// Phase A: approximate distance + argmin with FMA (contract ON).  Since z2
// is row-constant, compares c = e2 - 2G.  Tracks best (v1,i1) AND runner-up
// value v2 per row; rows whose gap could not separate np's quantized argmin
// (gap < GAP_THRESH, bound ~1.6e-4) are re-decided exactly in phase B.
// Block: 128 rows x 512 codes, 256 threads (16 tx x 16 ty), 8x8 accs,
// half-split tiles, code-split across 2 blocks (grid 1024 = 4 blocks/CU).
// ---------------------------------------------------------------------------
struct StageMem {
  float zs[KC][RT];              // 16 KiB  [k][row]
  float es[KC][ESTRIDE];         // 16.5 KiB [k][code]
};
struct RedMem {
  float rv[RT][17];
  int   ri[RT][17];
  float rv2[RT][17];
};

__global__ __launch_bounds__(256, 4) void dist_argmin_kernel(
    const float* __restrict__ z, const float* __restrict__ cb,
    const float* __restrict__ e2,
    float* __restrict__ pv1, float* __restrict__ pv2, int* __restrict__ pi) {
#pragma clang fp contract(fast)
  __shared__ union SMem {
    StageMem st;
    RedMem   rd;
  } sm;

  const int bid  = blockIdx.x;
  const int half = bid & 1;               // code half
  const int rt   = bid >> 1;              // row tile 0..511
  const int b    = rt >> 4;
  const int t0   = (rt & 15) << 7;
  const int n_base = half * NHALF;
  const int tid = threadIdx.x;
  const int tx  = tid & 15;               // code group
  const int ty  = tid >> 4;               // row group

  const float* zb = z + (size_t)b * CDIM * TT + t0;

  // staging coordinates: 32 quads x 8 k-groups
  const int c4 = tid & 31;
  const int kq = tid >> 5;

  float bv1[8], bv2[8];
  int   bi1[8];
#pragma unroll
  for (int r = 0; r < 8; r++) {
    bv1[r] = __builtin_inff();
    bv2[r] = __builtin_inff();
    bi1[r] = 0;
  }

  for (int n0 = n_base; n0 < n_base + NHALF; n0 += CT) {
    v2f acc2[8][4];
#pragma unroll
    for (int r = 0; r < 8; r++)
#pragma unroll
      for (int j = 0; j < 4; j++) acc2[r][j] = (v2f){0.0f, 0.0f};

    for (int kc = 0; kc < CDIM; kc += KC) {
      __syncthreads();
      // stage z: 32 k x 128 t, float4 in / b128 out
#pragma unroll
      for (int h = 0; h < 4; h++) {
        int k = kq + 8 * h;
        float4 v = *(const float4*)(zb + (size_t)(kc + k) * TT + c4 * 4);
        *(float4*)&sm.st.zs[k][c4 * 4] = v;
      }
      // stage cb: 32 k x 128 codes, transposed gather -> b128 writes
#pragma unroll
      for (int h = 0; h < 4; h++) {
        int k = kq + 8 * h;
        float4 v;
        v.x = cb[(size_t)(n0 + c4 * 4 + 0) * CDIM + kc + k];
        v.y = cb[(size_t)(n0 + c4 * 4 + 1) * CDIM + kc + k];
        v.z = cb[(size_t)(n0 + c4 * 4 + 2) * CDIM + kc + k];
        v.w = cb[(size_t)(n0 + c4 * 4 + 3) * CDIM + kc + k];
        *(float4*)&sm.st.es[k][c4 * 4] = v;
      }
      __syncthreads();

#pragma unroll 4
      for (int k = 0; k < KC; k++) {
        float za[8];
        *(float4*)&za[0] = *(const float4*)&sm.st.zs[k][ty * 4];
        *(float4*)&za[4] = *(const float4*)&sm.st.zs[k][64 + ty * 4];
        float4 e0 = *(const float4*)&sm.st.es[k][tx * 4];
        float4 e1 = *(const float4*)&sm.st.es[k][64 + tx * 4];
        v2f ea2[4];
        ea2[0] = (v2f){e0.x, e0.y};
        ea2[1] = (v2f){e0.z, e0.w};
        ea2[2] = (v2f){e1.x, e1.y};
        ea2[3] = (v2f){e1.z, e1.w};
#pragma unroll
        for (int r = 0; r < 8; r++) {
          v2f zr = (v2f){za[r], za[r]};
#pragma unroll
          for (int j = 0; j < 4; j++)
            acc2[r][j] = zr * ea2[j] + acc2[r][j];   // contract -> fma/pk_fma
        }
      }
    }

    // chunk epilogue: c = e2 - 2G; track best + runner-up
#pragma unroll
    for (int j = 0; j < 8; j++) {
      int   code = n0 + ((j < 4) ? (tx * 4 + j) : (64 + tx * 4 + (j - 4)));
      float e2c  = e2[code];
#pragma unroll
      for (int r = 0; r < 8; r++) {
        float a  = acc2[r][j >> 1][j & 1];
        float cv = e2c - 2.0f * a;
        if (cv < bv1[r]) {
          bv2[r] = bv1[r];
          bv1[r] = cv;
          bi1[r] = code;
        } else if (cv < bv2[r]) {
          bv2[r] = cv;
        }
      }
    }
  }

  __syncthreads();
#pragma unroll
  for (int r = 0; r < 8; r++) {
    int row = (r < 4) ? (ty * 4 + r) : (64 + ty * 4 + (r - 4));
    sm.rd.rv[row][tx]  = bv1[r];
    sm.rd.ri[row][tx]  = bi1[r];
    sm.rd.rv2[row][tx] = bv2[r];
  }
  __syncthreads();
  if (tid < RT) {
    float v1 = sm.rd.rv[tid][0];
    int   i1 = sm.rd.ri[tid][0];
    float v2 = sm.rd.rv2[tid][0];
#pragma unroll
    for (int x = 1; x < 16; x++) {
      float w1 = sm.rd.rv[tid][x];
      int   wi = sm.rd.ri[tid][x];
      float w2 = sm.rd.rv2[tid][x];
      if (w1 < v1) {
        v2 = fminf(w2, v1);
        v1 = w1;
        i1 = wi;
      } else {
        v2 = fminf(v2, w1);   // w2 >= w1, so w1 covers it
      }
    }
    int row = b * TT + t0 + tid;
    pv1[half * NROWS + row] = v1;
    pv2[half * NROWS + row] = v2;
    pi[half * NROWS + row]  = i1;
  }
}

// merge halves, write provisional idx, flag contested rows for exact redo
__global__ __launch_bounds__(256) void combine_flag_kernel(
    const float* __restrict__ pv1, const float* __restrict__ pv2,
    const int* __restrict__ pi, int* __restrict__ out_idx,
    int* __restrict__ flagcnt, int* __restrict__ list) {
  int n = blockIdx.x * 256 + threadIdx.x;
  if (n >= NROWS) return;
  float a1 = pv1[n],         a2 = pv2[n];
  float b1 = pv1[NROWS + n], b2 = pv2[NROWS + n];
  int   ai = pi[n],          bi = pi[NROWS + n];
  float v1, v2;
  int   i1;
  if (b1 < a1) { v1 = b1; i1 = bi; v2 = fminf(b2, a1); }
  else         { v1 = a1; i1 = ai; v2 = fminf(a2, b1); }
  out_idx[n] = i1;
  if (v2 - v1 < GAP_THRESH) {
    int p = atomicAdd(flagcnt, 1);
    list[p] = n;
  }
}

// ---------------------------------------------------------------------------
// Phase B: bit-exact np-chain re-decision for flagged rows.  Per (row,code):
// single fp32 accumulator, k = 0..255 sequential mul-then-add (contract
// off), d = fl( fl(z2+e2) - fl(2*G) ), first-occurrence argmin.
// Fixed grid; blocks grid-stride over the flagged list (graph-safe).
// ---------------------------------------------------------------------------
__global__ __launch_bounds__(256) void exact_fix_kernel(
    const float* __restrict__ z, const float* __restrict__ cb,
    const float* __restrict__ z2, const float* __restrict__ e2,
    const int* __restrict__ flagcnt, const int* __restrict__ list,
    int* __restrict__ out_idx) {
#pragma clang fp contract(off)
  __shared__ float sz[CDIM];
  __shared__ float rv[256];
  __shared__ int   ri[256];
  const int tid = threadIdx.x;
  const int cnt = *flagcnt;
  for (int it = blockIdx.x; it < cnt; it += gridDim.x) {
    int row = list[it];
    int b = row >> 11, t = row & (TT - 1);
    __syncthreads();                       // protect sz reuse across rows
    sz[tid] = z[(size_t)b * CDIM * TT + (size_t)tid * TT + t];
    __syncthreads();
    float z2v = z2[row];
    float bvv = __builtin_inff();
    int   bii = 0;
    for (int q = 0; q < 4; q++) {
      int code = tid * 4 + q;              // ascending within thread
      const float* cr = cb + (size_t)code * CDIM;
      float acc = 0.0f;
#pragma unroll 8
      for (int k = 0; k < CDIM; k++) {
        float p = sz[k] * cr[k];           // np chain: mul then add
        acc += p;
      }
      float s = z2v + e2[code];
      float d = s - 2.0f * acc;
      if (d < bvv) { bvv = d; bii = code; }
    }
    rv[tid] = bvv;
    ri[tid] = bii;
    __syncthreads();
    for (int st = 128; st > 0; st >>= 1) {
      if (tid < st) {
        float o  = rv[tid + st];
        int   oi = ri[tid + st];
        if (o < rv[tid] || (o == rv[tid] && oi < ri[tid])) {
          rv[tid] = o;
          ri[tid] = oi;
        }
      }
      __syncthreads();
    }
    if (tid == 0) out_idx[row] = ri[0];
  }
}

// ---------------------------------------------------------------------------
// Gather z_q, straight-through output fl(z + fl(zq - z)), loss accumulation
// ---------------------------------------------------------------------------
__global__ __launch_bounds__(256) void zq_loss_kernel(
    const float* __restrict__ z, const float* __restrict__ cb,
    const int* __restrict__ idx, float* __restrict__ zq_out,
    double* __restrict__ loss_acc) {
#pragma clang fp contract(off)
  __shared__ double sh[256];
  double local = 0.0;
  int stride = gridDim.x * blockDim.x;
  for (int i = blockIdx.x * blockDim.x + threadIdx.x; i < NELEM; i += stride) {
    int t = i & (TT - 1);
    int b = i >> 19;
    int c = (i >> 11) & (CDIM - 1);
    int n = (b << 11) | t;
    float zq   = cb[(size_t)idx[n] * CDIM + c];
    float zv   = z[i];
    float diff = zq - zv;
    zq_out[i]  = zv + diff;
    float sq   = diff * diff;
    local += (double)sq;
  }
  sh[threadIdx.x] = local;
  __syncthreads();
  for (int s = 128; s > 0; s >>= 1) {
    if (threadIdx.x < s) sh[threadIdx.x] += sh[threadIdx.x + s];
    __syncthreads();
  }
  if (threadIdx.x == 0) atomicAdd(loss_acc, sh[0]);
}

// one-hot (every element written once) + indices output + histogram
__global__ __launch_bounds__(256) void onehot_kernel(
    const int* __restrict__ idx, float* __restrict__ oh,
    float* __restrict__ idx_out, int* __restrict__ cnt) {
  int row  = blockIdx.x * 4 + (threadIdx.x >> 6);
  int lane = threadIdx.x & 63;
  int k    = idx[row];
  if (lane == 0) {
    idx_out[row] = (float)k;
    atomicAdd(&cnt[k], 1);
  }
  float4* dst = (float4*)(oh + (size_t)row * NE);
#pragma unroll
  for (int i = 0; i < 4; i++) {
    int c4   = i * 64 + lane;
    int base = c4 * 4;
    float4 v = {0.f, 0.f, 0.f, 0.f};
    if (k >= base && k < base + 4) ((float*)&v)[k - base] = 1.0f;
    dst[c4] = v;
  }
}

__global__ __launch_bounds__(1024) void finalize_kernel(
    const int* __restrict__ cnt, const double* __restrict__ loss_acc,
    float* __restrict__ out_loss, float* __restrict__ out_perp) {
#pragma clang fp contract(off)
  __shared__ float sh[1024];
  int t = threadIdx.x;
  float em = (float)cnt[t] / 65536.0f;
  sh[t] = em * logf(em + 1e-10f);
  __syncthreads();
  for (int s = 512; s > 0; s >>= 1) {
    if (t < s) sh[t] += sh[t + s];
    __syncthreads();
  }
  if (t == 0) {
    *out_perp = expf(-sh[0]);
    double m  = *loss_acc / (double)NELEM;
    float mf  = (float)m;
    float bt  = 0.25f * mf;
    *out_loss = mf + bt;
  }
}

// ---------------------------------------------------------------------------
extern "C" void kernel_launch(void* const* d_in, const int* in_sizes, int n_in,
                              void* d_out, int out_size, void* d_ws,
                              size_t ws_size, hipStream_t stream) {
  const float* z  = (const float*)d_in[0];
  const float* cb = (const float*)d_in[1];
  float* out = (float*)d_out;

  // workspace layout
  int*    ws_idx   = (int*)d_ws;                 // 65536 ints
  int*    ws_cnt   = ws_idx + NROWS;             // 1024 ints
  int*    ws_fcnt  = ws_cnt + NE;                // 1 int (+1 pad)
  double* ws_loss  = (double*)(ws_fcnt + 2);     // 8-aligned
  float*  ws_e2    = (float*)(ws_loss + 1);      // 1024 floats
  float*  ws_z2    = ws_e2 + NE;                 // 65536 floats
  float*  ws_pv1   = ws_z2 + NROWS;              // 2*65536 floats
  float*  ws_pv2   = ws_pv1 + 2 * NROWS;         // 2*65536 floats
  int*    ws_pi    = (int*)(ws_pv2 + 2 * NROWS); // 2*65536 ints
  int*    ws_list  = ws_pi + 2 * NROWS;          // 65536 ints

  // output layout (flat fp32 concat, reference return order)
  float* out_loss = out;
  float* out_zq   = out + 1;
  float* out_perp = out + 1 + (size_t)NELEM;
  float* out_oh   = out + 2 + (size_t)NELEM;
  float* out_idx  = out + 2 + (size_t)NELEM + (size_t)NROWS * NE;

  // zero: code-histogram, flag counter, loss accumulator
  hipMemsetAsync(ws_cnt, 0, (NE + 2) * sizeof(int) + sizeof(double), stream);

  e2_kernel<<<NE / 256, 256, 0, stream>>>(cb, ws_e2);
  z2_kernel<<<NROWS / 256, 256, 0, stream>>>(z, ws_z2);
  dist_argmin_kernel<<<(NROWS / RT) * 2, 256, 0, stream>>>(z, cb, ws_e2,
                                                           ws_pv1, ws_pv2,
                                                           ws_pi);
  combine_flag_kernel<<<NROWS / 256, 256, 0, stream>>>(ws_pv1, ws_pv2, ws_pi,
                                                       ws_idx, ws_fcnt,
                                                       ws_list);
  exact_fix_kernel<<<1024, 256, 0, stream>>>(z, cb, ws_z2, ws_e2, ws_fcnt,
                                             ws_list, ws_idx);
  zq_loss_kernel<<<2048, 256, 0, stream>>>(z, cb, ws_idx, out_zq, ws_loss);
  onehot_kernel<<<NROWS / 4, 256, 0, stream>>>(ws_idx, out_oh, out_idx,
                                               ws_cnt);
  finalize_kernel<<<1, 1024, 0, stream>>>(ws_cnt, ws_loss, out_loss, out_perp);
}

// Round 6
// 1361.187 us; speedup vs baseline: 1.2324x; 1.2324x over previous
//
#include <hip/hip_runtime.h>

#define BB    32
#define CDIM  256
#define TT    2048
#define NE    1024
#define NROWS (BB * TT)          // 65536
#define NELEM (BB * CDIM * TT)   // 16777216

// phase A tiling
#define RT 128                   // rows per block
#define CT 128                   // codes per chunk
#define KC 32                    // k's per LDS stage
#define NHALF 512                // codes per block (code-split factor 2)
#define ESTRIDE 132              // es row stride (16B-aligned rows)
// decision bound: np d-quantization 2*ulp(256)=6.2e-5 + chain diff 1.2e-5
// => orderings provably agree when c-gap > 7.4e-5.  2x margin:
#define GAP_THRESH 1.5e-4f
// phase B tiling
#define FBR 64                   // flagged rows per block

typedef float v2f __attribute__((ext_vector_type(2)));

// ---------------------------------------------------------------------------
// numpy pairwise sum of squares over 128 elements (stride in elements):
// 8 partials, combined ((r0+r1)+(r2+r3)) + ((r4+r5)+(r6+r7)).  contract OFF.
// ---------------------------------------------------------------------------
__device__ __forceinline__ float np_sq_sum128(const float* p, int stride) {
#pragma clang fp contract(off)
  float r[8];
#pragma unroll
  for (int j = 0; j < 8; j++) {
    float v = p[(size_t)j * stride];
    r[j] = v * v;
  }
  for (int i = 8; i < 128; i += 8) {
#pragma unroll
    for (int j = 0; j < 8; j++) {
      float v = p[(size_t)(i + j) * stride];
      float s = v * v;
      r[j] += s;
    }
  }
  return ((r[0] + r[1]) + (r[2] + r[3])) + ((r[4] + r[5]) + (r[6] + r[7]));
}

__global__ __launch_bounds__(256) void e2_kernel(const float* __restrict__ cb,
                                                 float* __restrict__ e2) {
#pragma clang fp contract(off)
  int k = blockIdx.x * 256 + threadIdx.x;
  if (k >= NE) return;
  const float* p = cb + (size_t)k * CDIM;
  float h0 = np_sq_sum128(p, 1);
  float h1 = np_sq_sum128(p + 128, 1);
  e2[k] = h0 + h1;
}

__global__ __launch_bounds__(256) void z2_kernel(const float* __restrict__ z,
                                                 float* __restrict__ z2) {
#pragma clang fp contract(off)
  int n = blockIdx.x * 256 + threadIdx.x;
  if (n >= NROWS) return;
  int b = n >> 11;
  int t = n & (TT - 1);
  const float* p = z + (size_t)b * CDIM * TT + t;
  float h0 = np_sq_sum128(p, TT);
  float h1 = np_sq_sum128(p + (size_t)128 * TT, TT);
  z2[n] = h0 + h1;
}

// cbT[k][code] = cb[code][k]  (1 MB; makes all staging coalesced)
__global__ __launch_bounds__(256) void transpose_cb_kernel(
    const float* __restrict__ cb, float* __restrict__ cbT) {
  __shared__ float t[32][33];
  int bid = blockIdx.x;
  int cx  = (bid & 31) << 5;            // code tile base
  int ky  = (bid >> 5) << 5;            // k tile base
  int lx  = threadIdx.x & 31;
  int ly  = threadIdx.x >> 5;           // 0..7
#pragma unroll
  for (int i = 0; i < 4; i++) {
    int code = cx + ly + 8 * i;
    t[ly + 8 * i][lx] = cb[(size_t)code * CDIM + ky + lx];
  }
  __syncthreads();
#pragma unroll
  for (int i = 0; i < 4; i++) {
    int k = ky + ly + 8 * i;
    cbT[(size_t)k * NE + cx + lx] = t[lx][ly + 8 * i];
  }
}

// ---------------------------------------------------------------------------
// Phase A: approximate argmin on c = e2 - 2G with FMA (contract ON), tracking
// best (v1,i1) and runner-up v2 per row.  Rows with v2-v1 < GAP_THRESH are
// re-decided bit-exactly in phase B.  Block: 128 rows x 512 codes, 256
// threads (16x16), 8x8 accs, half-split tiles; grid 1024 = 4 blocks/CU.
// ---------------------------------------------------------------------------
struct StageMem {
  float zs[KC][RT];              // 16 KiB  [k][row]
  float es[KC][ESTRIDE];         // 16.5 KiB [k][code]
};
struct RedMem {
  float rv[RT][17];
  int   ri[RT][17];
  float rv2[RT][17];
};

__global__ __launch_bounds__(256, 4) void dist_argmin_kernel(
    const float* __restrict__ z, const float* __restrict__ cbT,
    const float* __restrict__ e2,
    float* __restrict__ pv1, float* __restrict__ pv2, int* __restrict__ pi) {
#pragma clang fp contract(fast)
  __shared__ union SMem {
    StageMem st;
    RedMem   rd;
  } sm;

  const int bid  = blockIdx.x;
  const int half = bid & 1;
  const int rt   = bid >> 1;
  const int b    = rt >> 4;
  const int t0   = (rt & 15) << 7;
  const int n_base = half * NHALF;
  const int tid = threadIdx.x;
  const int tx  = tid & 15;
  const int ty  = tid >> 4;

  const float* zb = z + (size_t)b * CDIM * TT + t0;

  const int c4 = tid & 31;
  const int kq = tid >> 5;               // 0..7

  float bv1[8], bv2[8];
  int   bi1[8];
#pragma unroll
  for (int r = 0; r < 8; r++) {
    bv1[r] = __builtin_inff();
    bv2[r] = __builtin_inff();
    bi1[r] = 0;
  }

  for (int n0 = n_base; n0 < n_base + NHALF; n0 += CT) {
    v2f acc2[8][4];
#pragma unroll
    for (int r = 0; r < 8; r++)
#pragma unroll
      for (int j = 0; j < 4; j++) acc2[r][j] = (v2f){0.0f, 0.0f};

    for (int kc = 0; kc < CDIM; kc += KC) {
      __syncthreads();
      // stage z: 32 k x 128 t, float4 in / b128 out (coalesced)
#pragma unroll
      for (int h = 0; h < 4; h++) {
        int k = kq + 8 * h;
        float4 v = *(const float4*)(zb + (size_t)(kc + k) * TT + c4 * 4);
        *(float4*)&sm.st.zs[k][c4 * 4] = v;
      }
      // stage cbT: 32 k x 128 codes, coalesced float4 loads + b128 writes
#pragma unroll
      for (int h = 0; h < 4; h++) {
        int k = kq + 8 * h;
        float4 v = *(const float4*)(cbT + (size_t)(kc + k) * NE + n0 + c4 * 4);
        *(float4*)&sm.st.es[k][c4 * 4] = v;
      }
      __syncthreads();

#pragma unroll 4
      for (int k = 0; k < KC; k++) {
        float za[8];
        *(float4*)&za[0] = *(const float4*)&sm.st.zs[k][ty * 4];
        *(float4*)&za[4] = *(const float4*)&sm.st.zs[k][64 + ty * 4];
        float4 e0 = *(const float4*)&sm.st.es[k][tx * 4];
        float4 e1 = *(const float4*)&sm.st.es[k][64 + tx * 4];
        v2f ea2[4];
        ea2[0] = (v2f){e0.x, e0.y};
        ea2[1] = (v2f){e0.z, e0.w};
        ea2[2] = (v2f){e1.x, e1.y};
        ea2[3] = (v2f){e1.z, e1.w};
#pragma unroll
        for (int r = 0; r < 8; r++) {
          v2f zr = (v2f){za[r], za[r]};
#pragma unroll
          for (int j = 0; j < 4; j++)
            acc2[r][j] = zr * ea2[j] + acc2[r][j];   // fma
        }
      }
    }

#pragma unroll
    for (int j = 0; j < 8; j++) {
      int   code = n0 + ((j < 4) ? (tx * 4 + j) : (64 + tx * 4 + (j - 4)));
      float e2c  = e2[code];
#pragma unroll
      for (int r = 0; r < 8; r++) {
        float a  = acc2[r][j >> 1][j & 1];
        float cv = e2c - 2.0f * a;
        if (cv < bv1[r]) {
          bv2[r] = bv1[r];
          bv1[r] = cv;
          bi1[r] = code;
        } else if (cv < bv2[r]) {
          bv2[r] = cv;
        }
      }
    }
  }

  __syncthreads();
#pragma unroll
  for (int r = 0; r < 8; r++) {
    int row = (r < 4) ? (ty * 4 + r) : (64 + ty * 4 + (r - 4));
    sm.rd.rv[row][tx]  = bv1[r];
    sm.rd.ri[row][tx]  = bi1[r];
    sm.rd.rv2[row][tx] = bv2[r];
  }
  __syncthreads();
  if (tid < RT) {
    float v1 = sm.rd.rv[tid][0];
    int   i1 = sm.rd.ri[tid][0];
    float v2 = sm.rd.rv2[tid][0];
#pragma unroll
    for (int x = 1; x < 16; x++) {
      float w1 = sm.rd.rv[tid][x];
      int   wi = sm.rd.ri[tid][x];
      float w2 = sm.rd.rv2[tid][x];
      if (w1 < v1) {
        v2 = fminf(w2, v1);
        v1 = w1;
        i1 = wi;
      } else {
        v2 = fminf(v2, w1);
      }
    }
    int row = b * TT + t0 + tid;
    pv1[half * NROWS + row] = v1;
    pv2[half * NROWS + row] = v2;
    pi[half * NROWS + row]  = i1;
  }
}

// merge halves, write provisional idx, flag contested rows
__global__ __launch_bounds__(256) void combine_flag_kernel(
    const float* __restrict__ pv1, const float* __restrict__ pv2,
    const int* __restrict__ pi, int* __restrict__ out_idx,
    int* __restrict__ flagcnt, int* __restrict__ list) {
  int n = blockIdx.x * 256 + threadIdx.x;
  if (n >= NROWS) return;
  float a1 = pv1[n],         a2 = pv2[n];
  float b1 = pv1[NROWS + n], b2 = pv2[NROWS + n];
  int   ai = pi[n],          bi = pi[NROWS + n];
  float v1, v2;
  int   i1;
  if (b1 < a1) { v1 = b1; i1 = bi; v2 = fminf(b2, a1); }
  else         { v1 = a1; i1 = ai; v2 = fminf(a2, b1); }
  out_idx[n] = i1;
  if (v2 - v1 < GAP_THRESH) {
    int p = atomicAdd(flagcnt, 1);
    list[p] = n;
  }
}

// ---------------------------------------------------------------------------
// Phase B: tiled bit-exact np-chain argmin over flagged rows.  64 rows x
// 1024 codes per block-group; 256 threads (16 tx x 16 ty); thread tile =
// 4 rows x 8 codes; K staged 32 at a time from cbT (coalesced).  Per
// (row,code): one fp32 accumulator, k = 0..255 sequential mul-then-add
// (contract off); d = fl( fl(z2+e2) - fl(2*G) ); first-occurrence argmin.
// ---------------------------------------------------------------------------
__global__ __launch_bounds__(256) void exact_fix_kernel(
    const float* __restrict__ z, const float* __restrict__ cbT,
    const float* __restrict__ z2, const float* __restrict__ e2,
    const int* __restrict__ flagcnt, const int* __restrict__ list,
    int* __restrict__ out_idx) {
#pragma clang fp contract(off)
  __shared__ float zs[KC][FBR];          // 8 KiB
  __shared__ float es[KC][ESTRIDE];      // 16.5 KiB
  __shared__ float rv[FBR][17];
  __shared__ int   ri[FBR][17];
  __shared__ int   rowsh[FBR];
  __shared__ int   bsh[FBR], tsh[FBR];

  const int tid = threadIdx.x;
  const int tx  = tid & 15;
  const int ty  = tid >> 4;
  const int cnt = *flagcnt;
  const int ngroups = (cnt + FBR - 1) / FBR;

  const int lr  = tid & 63;              // z-staging row
  const int zkq = tid >> 6;              // 0..3
  const int c4  = tid & 31;              // es-staging quad
  const int ekq = tid >> 5;              // 0..7

  for (int g = blockIdx.x; g < ngroups; g += gridDim.x) {
    __syncthreads();
    if (tid < FBR) {
      int li  = g * FBR + tid;
      int row = (li < cnt) ? list[li] : list[cnt - 1];
      rowsh[tid] = row;
      bsh[tid]   = row >> 11;
      tsh[tid]   = row & (TT - 1);
    }
    __syncthreads();

    float z2r[4];
#pragma unroll
    for (int r = 0; r < 4; r++) z2r[r] = z2[rowsh[ty * 4 + r]];

    float bvv[4];
    int   bii[4];
#pragma unroll
    for (int r = 0; r < 4; r++) { bvv[r] = __builtin_inff(); bii[r] = 0; }

    for (int n0 = 0; n0 < NE; n0 += CT) {
      float acc[4][8];
#pragma unroll
      for (int r = 0; r < 4; r++)
#pragma unroll
        for (int j = 0; j < 8; j++) acc[r][j] = 0.0f;

      for (int kc = 0; kc < CDIM; kc += KC) {
        __syncthreads();
        // stage z rows (scattered, small volume: flagged rows only)
        {
          int bb = bsh[lr], tt = tsh[lr];
          const float* zp = z + (size_t)bb * CDIM * TT + tt;
#pragma unroll
          for (int h = 0; h < 8; h++) {
            int k = zkq * 8 + h;
            zs[k][lr] = zp[(size_t)(kc + k) * TT];
          }
        }
        // stage cbT chunk (coalesced)
#pragma unroll
        for (int h = 0; h < 4; h++) {
          int k = ekq + 8 * h;
          float4 v = *(const float4*)(cbT + (size_t)(kc + k) * NE + n0 + c4 * 4);
          *(float4*)&es[k][c4 * 4] = v;
        }
        __syncthreads();

#pragma unroll 4
        for (int k = 0; k < KC; k++) {
          float za[4], ea[8];
          *(float4*)&za[0] = *(const float4*)&zs[k][ty * 4];
          *(float4*)&ea[0] = *(const float4*)&es[k][tx * 4];
          *(float4*)&ea[4] = *(const float4*)&es[k][64 + tx * 4];
#pragma unroll
          for (int r = 0; r < 4; r++)
#pragma unroll
            for (int j = 0; j < 8; j++) {
              float p = za[r] * ea[j];     // np chain: mul then add
              acc[r][j] += p;
            }
        }
      }

#pragma unroll
      for (int j = 0; j < 8; j++) {
        int   code = n0 + ((j < 4) ? (tx * 4 + j) : (64 + tx * 4 + (j - 4)));
        float e2c  = e2[code];
#pragma unroll
        for (int r = 0; r < 4; r++) {
          float s = z2r[r] + e2c;
          float d = s - 2.0f * acc[r][j];
          if (d < bvv[r]) { bvv[r] = d; bii[r] = code; }
        }
      }
    }

    __syncthreads();
#pragma unroll
    for (int r = 0; r < 4; r++) {
      rv[ty * 4 + r][tx] = bvv[r];
      ri[ty * 4 + r][tx] = bii[r];
    }
    __syncthreads();
    if (tid < FBR) {
      float v  = rv[tid][0];
      int   ii = ri[tid][0];
#pragma unroll
      for (int x = 1; x < 16; x++) {
        float o  = rv[tid][x];
        int   oi = ri[tid][x];
        if (o < v || (o == v && oi < ii)) { v = o; ii = oi; }
      }
      if (g * FBR + tid < cnt) out_idx[rowsh[tid]] = ii;
    }
  }
}

// ---------------------------------------------------------------------------
// Gather z_q via LDS-staged codebook rows, straight-through output,
// loss accumulation.  Block = one b x 32-t tile; 2048 blocks.
// ---------------------------------------------------------------------------
__global__ __launch_bounds__(256) void zq_loss_kernel(
    const float* __restrict__ z, const float* __restrict__ cb,
    const int* __restrict__ idx, float* __restrict__ zq_out,
    double* __restrict__ loss_acc) {
#pragma clang fp contract(off)
  __shared__ float  crow[32][260];       // 32.5 KiB, 16B-aligned rows
  __shared__ int    kidx[32];
  __shared__ double sh[256];
  const int bid = blockIdx.x;
  const int b   = bid >> 6;
  const int t0  = (bid & 63) << 5;
  const int tid = threadIdx.x;
  if (tid < 32) kidx[tid] = idx[(b << 11) + t0 + tid];
  __syncthreads();
  {
    int rr = tid >> 3, part = tid & 7;
    const float4* src = (const float4*)(cb + (size_t)kidx[rr] * CDIM);
#pragma unroll
    for (int ii = 0; ii < 8; ii++) {
      int f4 = part + 8 * ii;
      *(float4*)&crow[rr][f4 * 4] = src[f4];
    }
  }
  __syncthreads();
  const int tt = tid & 31, cg = tid >> 5;
  double local = 0.0;
  const size_t base = (size_t)b * CDIM * TT + t0 + tt;
#pragma unroll 4
  for (int c = cg; c < CDIM; c += 8) {
    size_t i   = base + (size_t)c * TT;
    float zv   = z[i];
    float zq   = crow[tt][c];
    float diff = zq - zv;
    zq_out[i]  = zv + diff;
    float sq   = diff * diff;
    local += (double)sq;
  }
  sh[tid] = local;
  __syncthreads();
  for (int s = 128; s > 0; s >>= 1) {
    if (tid < s) sh[tid] += sh[tid + s];
    __syncthreads();
  }
  if (tid == 0) atomicAdd(loss_acc, sh[0]);
}

// one-hot (every element written once) + indices output + histogram
__global__ __launch_bounds__(256) void onehot_kernel(
    const int* __restrict__ idx, float* __restrict__ oh,
    float* __restrict__ idx_out, int* __restrict__ cnt) {
  int row  = blockIdx.x * 4 + (threadIdx.x >> 6);
  int lane = threadIdx.x & 63;
  int k    = idx[row];
  if (lane == 0) {
    idx_out[row] = (float)k;
    atomicAdd(&cnt[k], 1);
  }
  float4* dst = (float4*)(oh + (size_t)row * NE);
#pragma unroll
  for (int i = 0; i < 4; i++) {
    int c4   = i * 64 + lane;
    int base = c4 * 4;
    float4 v = {0.f, 0.f, 0.f, 0.f};
    if (k >= base && k < base + 4) ((float*)&v)[k - base] = 1.0f;
    dst[c4] = v;
  }
}

__global__ __launch_bounds__(1024) void finalize_kernel(
    const int* __restrict__ cnt, const double* __restrict__ loss_acc,
    float* __restrict__ out_loss, float* __restrict__ out_perp) {
#pragma clang fp contract(off)
  __shared__ float sh[1024];
  int t = threadIdx.x;
  float em = (float)cnt[t] / 65536.0f;
  sh[t] = em * logf(em + 1e-10f);
  __syncthreads();
  for (int s = 512; s > 0; s >>= 1) {
    if (t < s) sh[t] += sh[t + s];
    __syncthreads();
  }
  if (t == 0) {
    *out_perp = expf(-sh[0]);
    double m  = *loss_acc / (double)NELEM;
    float mf  = (float)m;
    float bt  = 0.25f * mf;
    *out_loss = mf + bt;
  }
}

// ---------------------------------------------------------------------------
extern "C" void kernel_launch(void* const* d_in, const int* in_sizes, int n_in,
                              void* d_out, int out_size, void* d_ws,
                              size_t ws_size, hipStream_t stream) {
  const float* z  = (const float*)d_in[0];
  const float* cb = (const float*)d_in[1];
  float* out = (float*)d_out;

  // workspace layout
  int*    ws_idx   = (int*)d_ws;                 // 65536 ints
  int*    ws_cnt   = ws_idx + NROWS;             // 1024 ints
  int*    ws_fcnt  = ws_cnt + NE;                // 1 int (+1 pad)
  double* ws_loss  = (double*)(ws_fcnt + 2);     // 8-aligned
  float*  ws_e2    = (float*)(ws_loss + 1);      // 1024 floats
  float*  ws_z2    = ws_e2 + NE;                 // 65536 floats
  float*  ws_pv1   = ws_z2 + NROWS;              // 2*65536 floats
  float*  ws_pv2   = ws_pv1 + 2 * NROWS;         // 2*65536 floats
  int*    ws_pi    = (int*)(ws_pv2 + 2 * NROWS); // 2*65536 ints
  int*    ws_list  = ws_pi + 2 * NROWS;          // 65536 ints
  float*  ws_cbT   = (float*)(ws_list + NROWS);  // 256*1024 floats (1 MB)

  // output layout (flat fp32 concat, reference return order)
  float* out_loss = out;
  float* out_zq   = out + 1;
  float* out_perp = out + 1 + (size_t)NELEM;
  float* out_oh   = out + 2 + (size_t)NELEM;
  float* out_idx  = out + 2 + (size_t)NELEM + (size_t)NROWS * NE;

  // zero: code-histogram, flag counter, loss accumulator
  hipMemsetAsync(ws_cnt, 0, (NE + 2) * sizeof(int) + sizeof(double), stream);

  transpose_cb_kernel<<<256, 256, 0, stream>>>(cb, ws_cbT);
  e2_kernel<<<NE / 256, 256, 0, stream>>>(cb, ws_e2);
  z2_kernel<<<NROWS / 256, 256, 0, stream>>>(z, ws_z2);
  dist_argmin_kernel<<<(NROWS / RT) * 2, 256, 0, stream>>>(z, ws_cbT, ws_e2,
                                                           ws_pv1, ws_pv2,
                                                           ws_pi);
  combine_flag_kernel<<<NROWS / 256, 256, 0, stream>>>(ws_pv1, ws_pv2, ws_pi,
                                                       ws_idx, ws_fcnt,
                                                       ws_list);
  exact_fix_kernel<<<256, 256, 0, stream>>>(z, ws_cbT, ws_z2, ws_e2, ws_fcnt,
                                            ws_list, ws_idx);
  zq_loss_kernel<<<NROWS / 32, 256, 0, stream>>>(z, cb, ws_idx, out_zq,
                                                 ws_loss);
  onehot_kernel<<<NROWS / 4, 256, 0, stream>>>(ws_idx, out_oh, out_idx,
                                               ws_cnt);
  finalize_kernel<<<1, 1024, 0, stream>>>(ws_cnt, ws_loss, out_loss, out_perp);
}